// Round 3
// baseline (254.450 us; speedup 1.0000x reference)
//
#include <hip/hip_runtime.h>

#define LENGTH 4000
#define NPAD   4096
#define NB     8
#define CH     64
#define NP     4
#define OSPLIT 8
#define OPB    (CH / OSPLIT)    // 8 outputs per block
#define NCHCOL 256              // n-columns per mix block
#define NCHUNKS (NPAD / NCHCOL) // 16

// ---------------- K1: forward FWHT of zero-padded x rows -> f1 ----------------
__global__ __launch_bounds__(256) void k_fwht_fwd(const float* __restrict__ x,
                                                  float* __restrict__ f1) {
    __shared__ float s[NPAD];
    const int row = blockIdx.x;            // b*64 + i
    const int t = threadIdx.x;
    const float* xr = x + (size_t)row * LENGTH;
    #pragma unroll
    for (int j = 0; j < NPAD / 256; ++j) {
        int n = j * 256 + t;
        s[n] = (n < LENGTH) ? xr[n] : 0.f;
    }
    for (int h = 1; h < NPAD; h <<= 1) {
        __syncthreads();
        #pragma unroll
        for (int j = 0; j < NPAD / 512; ++j) {
            int k = j * 256 + t;
            int idx = ((k & ~(h - 1)) << 1) | (k & (h - 1));
            float a = s[idx], c = s[idx + h];
            s[idx] = a + c;
            s[idx + h] = a - c;
        }
    }
    __syncthreads();
    float* fr = f1 + (size_t)row * NPAD;
    #pragma unroll
    for (int j = 0; j < NPAD / 256; ++j) {
        int n = j * 256 + t;
        fr[n] = s[n];
    }
}

// ---------------- K2: per-column channel mix + soft-threshold + sum over p ----
// W slab for this block's o-range staged in LDS; read back via uniform-address
// ds_read_b128 (broadcast) so the dot loop pipelines through VGPRs, not SGPRs.
__global__ void k_mix(const float* __restrict__ f1,
                      const float* __restrict__ W,
                      const float* __restrict__ T,
                      const float* __restrict__ v,
                      float* __restrict__ f6) {
    __shared__ float sW[NP][OPB][CH];      // 8 KB
    const int bid = blockIdx.x;            // b*(NCHUNKS*OSPLIT) + chunk*OSPLIT + oq
    const int oq = bid & (OSPLIT - 1);
    const int chunk = (bid >> 3) & (NCHUNKS - 1);
    const int b = bid >> 7;
    const int t = threadIdx.x;
    const int n = chunk * NCHCOL + t;

    // stage W[p, oq*OPB + o, i] -> sW[p][o][i]; 2048 floats = 512 float4
    #pragma unroll
    for (int r = 0; r < 2; ++r) {
        int q = r * 256 + t;               // float4 index 0..511
        int p = q >> 7;                    // 128 float4 per p
        int rem = q & 127;
        int o = rem >> 4, i4 = rem & 15;   // 16 float4 per row
        float4 w = *(const float4*)(W + ((size_t)(p * CH + oq * OPB + o) * CH + i4 * 4));
        *(float4*)(&sW[p][o][i4 * 4]) = w;
    }

    float col[CH];
    const float* f1c = f1 + (size_t)b * CH * NPAD + n;
    #pragma unroll
    for (int i = 0; i < CH; ++i)
        col[i] = f1c[(size_t)i * NPAD];

    float vp[NP], tp[NP];
    #pragma unroll
    for (int p = 0; p < NP; ++p) {
        vp[p] = v[p * NPAD + n];
        tp[p] = fabsf(T[p * NPAD + n]);
    }
    __syncthreads();

    float* f6c = f6 + (size_t)(b * CH + oq * OPB) * NPAD + n;
    for (int o = 0; o < OPB; ++o) {
        float acc = 0.f;
        #pragma unroll
        for (int p = 0; p < NP; ++p) {
            const float4* wr = (const float4*)&sW[p][o][0];
            float g0 = 0.f, g1 = 0.f, g2 = 0.f, g3 = 0.f;
            #pragma unroll
            for (int i = 0; i < CH / 4; ++i) {
                float4 w = wr[i];
                g0 = fmaf(w.x, col[4 * i],     g0);
                g1 = fmaf(w.y, col[4 * i + 1], g1);
                g2 = fmaf(w.z, col[4 * i + 2], g2);
                g3 = fmaf(w.w, col[4 * i + 3], g3);
            }
            float c = vp[p] * ((g0 + g1) + (g2 + g3));
            float a = fabsf(c) - tp[p];
            acc += (a > 0.f) ? copysignf(a, c) : 0.f;
        }
        f6c[(size_t)o * NPAD] = acc;
    }
}

// ---------------- K3: inverse FWHT (scaled), truncate, add x -> out -----------
__global__ __launch_bounds__(256) void k_fwht_inv(const float* __restrict__ f6,
                                                  const float* __restrict__ x,
                                                  float* __restrict__ out) {
    __shared__ float s[NPAD];
    const int row = blockIdx.x;            // b*64 + o
    const int t = threadIdx.x;
    const float* fr = f6 + (size_t)row * NPAD;
    #pragma unroll
    for (int j = 0; j < NPAD / 256; ++j) {
        int n = j * 256 + t;
        s[n] = fr[n];
    }
    for (int h = 1; h < NPAD; h <<= 1) {
        __syncthreads();
        #pragma unroll
        for (int j = 0; j < NPAD / 512; ++j) {
            int k = j * 256 + t;
            int idx = ((k & ~(h - 1)) << 1) | (k & (h - 1));
            float a = s[idx], c = s[idx + h];
            s[idx] = a + c;
            s[idx + h] = a - c;
        }
    }
    __syncthreads();
    const float* xr = x + (size_t)row * LENGTH;
    float* orow = out + (size_t)row * LENGTH;
    const float scale = 1.f / NPAD;
    #pragma unroll
    for (int j = 0; j < NPAD / 256; ++j) {
        int n = j * 256 + t;
        if (n < LENGTH) orow[n] = s[n] * scale + xr[n];
    }
}

extern "C" void kernel_launch(void* const* d_in, const int* in_sizes, int n_in,
                              void* d_out, int out_size, void* d_ws, size_t ws_size,
                              hipStream_t stream) {
    (void)in_sizes; (void)n_in; (void)out_size; (void)ws_size;
    const float* x = (const float*)d_in[0];
    const float* W = (const float*)d_in[1];
    const float* T = (const float*)d_in[2];
    const float* v = (const float*)d_in[3];
    float* out = (float*)d_out;
    float* f1 = (float*)d_ws;
    float* f6 = f1 + (size_t)NB * CH * NPAD;

    k_fwht_fwd<<<NB * CH, 256, 0, stream>>>(x, f1);
    k_mix<<<NB * NCHUNKS * OSPLIT, 256, 0, stream>>>(f1, W, T, v, f6);
    k_fwht_inv<<<NB * CH, 256, 0, stream>>>(f6, x, out);
}

// Round 4
// 168.548 us; speedup vs baseline: 1.5097x; 1.5097x over previous
//
#include <hip/hip_runtime.h>

#define LENGTH 4000
#define NPAD   4096
#define NB     8
#define CH     64
#define NP     4
#define OSPLIT 8
#define OPB    (CH / OSPLIT)    // 8 outputs per block
#define NCHCOL 256              // n-columns per mix block
#define NCHUNKS (NPAD / NCHCOL) // 16

// ---------------- K1: forward FWHT of zero-padded x rows -> f1 ----------------
__global__ __launch_bounds__(256) void k_fwht_fwd(const float* __restrict__ x,
                                                  float* __restrict__ f1) {
    __shared__ float s[NPAD];
    const int row = blockIdx.x;            // b*64 + i
    const int t = threadIdx.x;
    const float* xr = x + (size_t)row * LENGTH;
    #pragma unroll
    for (int j = 0; j < NPAD / 256; ++j) {
        int n = j * 256 + t;
        s[n] = (n < LENGTH) ? xr[n] : 0.f;
    }
    for (int h = 1; h < NPAD; h <<= 1) {
        __syncthreads();
        #pragma unroll
        for (int j = 0; j < NPAD / 512; ++j) {
            int k = j * 256 + t;
            int idx = ((k & ~(h - 1)) << 1) | (k & (h - 1));
            float a = s[idx], c = s[idx + h];
            s[idx] = a + c;
            s[idx + h] = a - c;
        }
    }
    __syncthreads();
    float* fr = f1 + (size_t)row * NPAD;
    #pragma unroll
    for (int j = 0; j < NPAD / 256; ++j) {
        int n = j * 256 + t;
        fr[n] = s[n];
    }
}

// ---------------- K2: per-column channel mix + soft-threshold + sum over p ----
// EXACT Round-1 structure (108 VGPR, no spill): col[] in VGPRs, W via
// wave-uniform scalar loads. Single change: OSPLIT 4 -> 8 for 4 waves/SIMD.
__global__ void k_mix(const float* __restrict__ f1,
                      const float* __restrict__ W,
                      const float* __restrict__ T,
                      const float* __restrict__ v,
                      float* __restrict__ f6) {
    const int bid = blockIdx.x;            // b*(NCHUNKS*OSPLIT) + chunk*OSPLIT + oq
    const int oq = bid & (OSPLIT - 1);
    const int chunk = (bid / OSPLIT) & (NCHUNKS - 1);
    const int b = bid / (OSPLIT * NCHUNKS);
    const int n = chunk * NCHCOL + threadIdx.x;

    float col[CH];
    #pragma unroll
    for (int i = 0; i < CH; ++i)
        col[i] = f1[(size_t)(b * CH + i) * NPAD + n];

    float vp[NP], tp[NP];
    #pragma unroll
    for (int p = 0; p < NP; ++p) {
        vp[p] = v[p * NPAD + n];
        tp[p] = fabsf(T[p * NPAD + n]);
    }

    for (int o = 0; o < OPB; ++o) {
        const int oo = oq * OPB + o;
        float acc = 0.f;
        #pragma unroll
        for (int p = 0; p < NP; ++p) {
            const float* wr = W + (size_t)(p * CH + oo) * CH;
            float g0 = 0.f, g1 = 0.f;
            #pragma unroll
            for (int i = 0; i < CH; i += 2) {
                g0 = fmaf(wr[i],     col[i],     g0);
                g1 = fmaf(wr[i + 1], col[i + 1], g1);
            }
            float c = vp[p] * (g0 + g1);
            float a = fabsf(c) - tp[p];
            acc += (a > 0.f) ? copysignf(a, c) : 0.f;
        }
        f6[(size_t)(b * CH + oo) * NPAD + n] = acc;
    }
}

// ---------------- K3: inverse FWHT (scaled), truncate, add x -> out -----------
__global__ __launch_bounds__(256) void k_fwht_inv(const float* __restrict__ f6,
                                                  const float* __restrict__ x,
                                                  float* __restrict__ out) {
    __shared__ float s[NPAD];
    const int row = blockIdx.x;            // b*64 + o
    const int t = threadIdx.x;
    const float* fr = f6 + (size_t)row * NPAD;
    #pragma unroll
    for (int j = 0; j < NPAD / 256; ++j) {
        int n = j * 256 + t;
        s[n] = fr[n];
    }
    for (int h = 1; h < NPAD; h <<= 1) {
        __syncthreads();
        #pragma unroll
        for (int j = 0; j < NPAD / 512; ++j) {
            int k = j * 256 + t;
            int idx = ((k & ~(h - 1)) << 1) | (k & (h - 1));
            float a = s[idx], c = s[idx + h];
            s[idx] = a + c;
            s[idx + h] = a - c;
        }
    }
    __syncthreads();
    const float* xr = x + (size_t)row * LENGTH;
    float* orow = out + (size_t)row * LENGTH;
    const float scale = 1.f / NPAD;
    #pragma unroll
    for (int j = 0; j < NPAD / 256; ++j) {
        int n = j * 256 + t;
        if (n < LENGTH) orow[n] = s[n] * scale + xr[n];
    }
}

extern "C" void kernel_launch(void* const* d_in, const int* in_sizes, int n_in,
                              void* d_out, int out_size, void* d_ws, size_t ws_size,
                              hipStream_t stream) {
    (void)in_sizes; (void)n_in; (void)out_size; (void)ws_size;
    const float* x = (const float*)d_in[0];
    const float* W = (const float*)d_in[1];
    const float* T = (const float*)d_in[2];
    const float* v = (const float*)d_in[3];
    float* out = (float*)d_out;
    float* f1 = (float*)d_ws;
    float* f6 = f1 + (size_t)NB * CH * NPAD;

    k_fwht_fwd<<<NB * CH, 256, 0, stream>>>(x, f1);
    k_mix<<<NB * NCHUNKS * OSPLIT, 256, 0, stream>>>(f1, W, T, v, f6);
    k_fwht_inv<<<NB * CH, 256, 0, stream>>>(f6, x, out);
}

// Round 5
// 160.388 us; speedup vs baseline: 1.5865x; 1.0509x over previous
//
#include <hip/hip_runtime.h>

#define LENGTH 4000
#define NPAD   4096
#define NB     8
#define CH     64
#define NP     4
#define OSPLIT 8
#define OPB    (CH / OSPLIT)    // 8 outputs per block
#define NCHCOL 256              // n-columns per mix block
#define NCHUNKS (NPAD / NCHCOL) // 16

// ---------------- K1: forward FWHT of zero-padded x rows -> f1 ----------------
__global__ __launch_bounds__(256) void k_fwht_fwd(const float* __restrict__ x,
                                                  float* __restrict__ f1) {
    __shared__ float s[NPAD];
    const int row = blockIdx.x;            // b*64 + i
    const int t = threadIdx.x;
    const float* xr = x + (size_t)row * LENGTH;
    #pragma unroll
    for (int j = 0; j < NPAD / 256; ++j) {
        int n = j * 256 + t;
        s[n] = (n < LENGTH) ? xr[n] : 0.f;
    }
    for (int h = 1; h < NPAD; h <<= 1) {
        __syncthreads();
        #pragma unroll
        for (int j = 0; j < NPAD / 512; ++j) {
            int k = j * 256 + t;
            int idx = ((k & ~(h - 1)) << 1) | (k & (h - 1));
            float a = s[idx], c = s[idx + h];
            s[idx] = a + c;
            s[idx + h] = a - c;
        }
    }
    __syncthreads();
    float* fr = f1 + (size_t)row * NPAD;
    #pragma unroll
    for (int j = 0; j < NPAD / 256; ++j) {
        int n = j * 256 + t;
        fr[n] = s[n];
    }
}

// ---------------- K2: per-column channel mix + soft-threshold + sum over p ----
// Round-1 codegen (rolled o-loop, 108 VGPR, no spill) + OSPLIT=8 occupancy.
// #pragma unroll 1 is load-bearing: full unroll of the o-loop makes the
// allocator pick a 64-VGPR budget and spill col[] to scratch (R2/R4).
__global__ void k_mix(const float* __restrict__ f1,
                      const float* __restrict__ W,
                      const float* __restrict__ T,
                      const float* __restrict__ v,
                      float* __restrict__ f6) {
    const int bid = blockIdx.x;            // b*(NCHUNKS*OSPLIT) + chunk*OSPLIT + oq
    const int oq = bid & (OSPLIT - 1);
    const int chunk = (bid / OSPLIT) & (NCHUNKS - 1);
    const int b = bid / (OSPLIT * NCHUNKS);
    const int n = chunk * NCHCOL + threadIdx.x;

    float col[CH];
    #pragma unroll
    for (int i = 0; i < CH; ++i)
        col[i] = f1[(size_t)(b * CH + i) * NPAD + n];

    float vp[NP], tp[NP];
    #pragma unroll
    for (int p = 0; p < NP; ++p) {
        vp[p] = v[p * NPAD + n];
        tp[p] = fabsf(T[p * NPAD + n]);
    }

    #pragma unroll 1
    for (int o = 0; o < OPB; ++o) {
        const int oo = oq * OPB + o;
        float acc = 0.f;
        #pragma unroll
        for (int p = 0; p < NP; ++p) {
            const float* wr = W + (size_t)(p * CH + oo) * CH;
            float g0 = 0.f, g1 = 0.f;
            #pragma unroll
            for (int i = 0; i < CH; i += 2) {
                g0 = fmaf(wr[i],     col[i],     g0);
                g1 = fmaf(wr[i + 1], col[i + 1], g1);
            }
            float c = vp[p] * (g0 + g1);
            float a = fabsf(c) - tp[p];
            acc += (a > 0.f) ? copysignf(a, c) : 0.f;
        }
        f6[(size_t)(b * CH + oo) * NPAD + n] = acc;
    }
}

// ---------------- K3: inverse FWHT (scaled), truncate, add x -> out -----------
__global__ __launch_bounds__(256) void k_fwht_inv(const float* __restrict__ f6,
                                                  const float* __restrict__ x,
                                                  float* __restrict__ out) {
    __shared__ float s[NPAD];
    const int row = blockIdx.x;            // b*64 + o
    const int t = threadIdx.x;
    const float* fr = f6 + (size_t)row * NPAD;
    #pragma unroll
    for (int j = 0; j < NPAD / 256; ++j) {
        int n = j * 256 + t;
        s[n] = fr[n];
    }
    for (int h = 1; h < NPAD; h <<= 1) {
        __syncthreads();
        #pragma unroll
        for (int j = 0; j < NPAD / 512; ++j) {
            int k = j * 256 + t;
            int idx = ((k & ~(h - 1)) << 1) | (k & (h - 1));
            float a = s[idx], c = s[idx + h];
            s[idx] = a + c;
            s[idx + h] = a - c;
        }
    }
    __syncthreads();
    const float* xr = x + (size_t)row * LENGTH;
    float* orow = out + (size_t)row * LENGTH;
    const float scale = 1.f / NPAD;
    #pragma unroll
    for (int j = 0; j < NPAD / 256; ++j) {
        int n = j * 256 + t;
        if (n < LENGTH) orow[n] = s[n] * scale + xr[n];
    }
}

extern "C" void kernel_launch(void* const* d_in, const int* in_sizes, int n_in,
                              void* d_out, int out_size, void* d_ws, size_t ws_size,
                              hipStream_t stream) {
    (void)in_sizes; (void)n_in; (void)out_size; (void)ws_size;
    const float* x = (const float*)d_in[0];
    const float* W = (const float*)d_in[1];
    const float* T = (const float*)d_in[2];
    const float* v = (const float*)d_in[3];
    float* out = (float*)d_out;
    float* f1 = (float*)d_ws;
    float* f6 = f1 + (size_t)NB * CH * NPAD;

    k_fwht_fwd<<<NB * CH, 256, 0, stream>>>(x, f1);
    k_mix<<<NB * NCHUNKS * OSPLIT, 256, 0, stream>>>(f1, W, T, v, f6);
    k_fwht_inv<<<NB * CH, 256, 0, stream>>>(f6, x, out);
}

// Round 6
// 46.748 us; speedup vs baseline: 5.4430x; 3.4309x over previous
//
#include <hip/hip_runtime.h>

#define LENGTH 4000
#define NPAD   4096
#define NB     8
#define CH     64
#define NP     4
#define NTILE  64               // n-columns per mix block

// ---------------- K1: forward FWHT of zero-padded x rows -> f1 ----------------
__global__ __launch_bounds__(256) void k_fwht_fwd(const float* __restrict__ x,
                                                  float* __restrict__ f1) {
    __shared__ float s[NPAD];
    const int row = blockIdx.x;            // b*64 + i
    const int t = threadIdx.x;
    const float* xr = x + (size_t)row * LENGTH;
    #pragma unroll
    for (int j = 0; j < NPAD / 256; ++j) {
        int n = j * 256 + t;
        s[n] = (n < LENGTH) ? xr[n] : 0.f;
    }
    for (int h = 1; h < NPAD; h <<= 1) {
        __syncthreads();
        #pragma unroll
        for (int j = 0; j < NPAD / 512; ++j) {
            int k = j * 256 + t;
            int idx = ((k & ~(h - 1)) << 1) | (k & (h - 1));
            float a = s[idx], c = s[idx + h];
            s[idx] = a + c;
            s[idx + h] = a - c;
        }
    }
    __syncthreads();
    float* fr = f1 + (size_t)row * NPAD;
    #pragma unroll
    for (int j = 0; j < NPAD / 256; ++j) {
        int n = j * 256 + t;
        fr[n] = s[n];
    }
}

// ---------------- K2: register-tiled channel mix ------------------------------
// Block: one b, 64 n-columns, all 64 o. Thread: static 4o x 4n tile.
// W[p] transposed into LDS per p (conflict-free), f1 tile in LDS once.
// NO per-thread arrays -> no spill cliff; no s_load serialization.
#define ST_APPLY(OUTC, AC, VPC, TPC)                                   \
    {                                                                  \
        float c_ = (VPC) * (AC);                                       \
        float aa_ = fabsf(c_) - fabsf(TPC);                            \
        (OUTC) += (aa_ > 0.f) ? copysignf(aa_, c_) : 0.f;              \
    }

__global__ __launch_bounds__(256) void k_mix(const float* __restrict__ f1,
                                             const float* __restrict__ W,
                                             const float* __restrict__ T,
                                             const float* __restrict__ v,
                                             float* __restrict__ f6) {
    __shared__ float sW[CH][CH];   // [i][o] for current p, 16 KB
    __shared__ float sC[CH][NTILE];// [i][n], 16 KB
    const int bid = blockIdx.x;    // b*64 + chunk
    const int chunk = bid & 63;
    const int b = bid >> 6;
    const int nbase = chunk * NTILE;
    const int t = threadIdx.x;
    const int tn = t & 15;         // n-group: 4 n's
    const int to = t >> 4;         // o-group: 4 o's
    const int o0 = to * 4, n0 = tn * 4;
    const int wo = t & 63;         // W staging: o index
    const int wib = t >> 6;        // W staging: i-block 0..3

    // stage f1 tile: sC[i][n]  (coalesced reads, dense b128 writes)
    #pragma unroll
    for (int r = 0; r < 4; ++r) {
        int q = r * 256 + t;
        int i = q >> 4, n4 = q & 15;
        float4 cv = *(const float4*)(f1 + (size_t)(b * CH + i) * NPAD + nbase + n4 * 4);
        *(float4*)(&sC[i][n4 * 4]) = cv;
    }

    float4 out0, out1, out2, out3;
    out0.x=out0.y=out0.z=out0.w=0.f; out1=out0; out2=out0; out3=out0;

    #pragma unroll 1
    for (int p = 0; p < NP; ++p) {
        __syncthreads();   // prior-p readers done (also covers sC staging at p=0)
        // stage W[p] transposed -> sW[i][o]; strided global reads (L1-hot),
        // stride-1 conflict-free ds_writes
        const float* wp = W + (size_t)(p * CH + wo) * CH + wib * 16;
        #pragma unroll
        for (int k4 = 0; k4 < 4; ++k4) {
            float4 wv = *(const float4*)(wp + k4 * 4);
            sW[wib * 16 + k4 * 4 + 0][wo] = wv.x;
            sW[wib * 16 + k4 * 4 + 1][wo] = wv.y;
            sW[wib * 16 + k4 * 4 + 2][wo] = wv.z;
            sW[wib * 16 + k4 * 4 + 3][wo] = wv.w;
        }
        __syncthreads();

        float4 a0, a1, a2, a3;
        a0.x=a0.y=a0.z=a0.w=0.f; a1=a0; a2=a0; a3=a0;
        #pragma unroll 8
        for (int i = 0; i < CH; ++i) {
            float4 w4 = *(const float4*)(&sW[i][o0]);   // 4-addr broadcast
            float4 c4 = *(const float4*)(&sC[i][n0]);   // 16-addr contiguous
            a0.x = fmaf(w4.x, c4.x, a0.x); a0.y = fmaf(w4.x, c4.y, a0.y);
            a0.z = fmaf(w4.x, c4.z, a0.z); a0.w = fmaf(w4.x, c4.w, a0.w);
            a1.x = fmaf(w4.y, c4.x, a1.x); a1.y = fmaf(w4.y, c4.y, a1.y);
            a1.z = fmaf(w4.y, c4.z, a1.z); a1.w = fmaf(w4.y, c4.w, a1.w);
            a2.x = fmaf(w4.z, c4.x, a2.x); a2.y = fmaf(w4.z, c4.y, a2.y);
            a2.z = fmaf(w4.z, c4.z, a2.z); a2.w = fmaf(w4.z, c4.w, a2.w);
            a3.x = fmaf(w4.w, c4.x, a3.x); a3.y = fmaf(w4.w, c4.y, a3.y);
            a3.z = fmaf(w4.w, c4.z, a3.z); a3.w = fmaf(w4.w, c4.w, a3.w);
        }
        float4 vp = *(const float4*)(v + (size_t)p * NPAD + nbase + n0);
        float4 tp = *(const float4*)(T + (size_t)p * NPAD + nbase + n0);
        ST_APPLY(out0.x, a0.x, vp.x, tp.x); ST_APPLY(out0.y, a0.y, vp.y, tp.y);
        ST_APPLY(out0.z, a0.z, vp.z, tp.z); ST_APPLY(out0.w, a0.w, vp.w, tp.w);
        ST_APPLY(out1.x, a1.x, vp.x, tp.x); ST_APPLY(out1.y, a1.y, vp.y, tp.y);
        ST_APPLY(out1.z, a1.z, vp.z, tp.z); ST_APPLY(out1.w, a1.w, vp.w, tp.w);
        ST_APPLY(out2.x, a2.x, vp.x, tp.x); ST_APPLY(out2.y, a2.y, vp.y, tp.y);
        ST_APPLY(out2.z, a2.z, vp.z, tp.z); ST_APPLY(out2.w, a2.w, vp.w, tp.w);
        ST_APPLY(out3.x, a3.x, vp.x, tp.x); ST_APPLY(out3.y, a3.y, vp.y, tp.y);
        ST_APPLY(out3.z, a3.z, vp.z, tp.z); ST_APPLY(out3.w, a3.w, vp.w, tp.w);
    }

    float* dst = f6 + (size_t)(b * CH + o0) * NPAD + nbase + n0;
    *(float4*)(dst + (size_t)0 * NPAD) = out0;
    *(float4*)(dst + (size_t)1 * NPAD) = out1;
    *(float4*)(dst + (size_t)2 * NPAD) = out2;
    *(float4*)(dst + (size_t)3 * NPAD) = out3;
}

// ---------------- K3: inverse FWHT (scaled), truncate, add x -> out -----------
__global__ __launch_bounds__(256) void k_fwht_inv(const float* __restrict__ f6,
                                                  const float* __restrict__ x,
                                                  float* __restrict__ out) {
    __shared__ float s[NPAD];
    const int row = blockIdx.x;            // b*64 + o
    const int t = threadIdx.x;
    const float* fr = f6 + (size_t)row * NPAD;
    #pragma unroll
    for (int j = 0; j < NPAD / 256; ++j) {
        int n = j * 256 + t;
        s[n] = fr[n];
    }
    for (int h = 1; h < NPAD; h <<= 1) {
        __syncthreads();
        #pragma unroll
        for (int j = 0; j < NPAD / 512; ++j) {
            int k = j * 256 + t;
            int idx = ((k & ~(h - 1)) << 1) | (k & (h - 1));
            float a = s[idx], c = s[idx + h];
            s[idx] = a + c;
            s[idx + h] = a - c;
        }
    }
    __syncthreads();
    const float* xr = x + (size_t)row * LENGTH;
    float* orow = out + (size_t)row * LENGTH;
    const float scale = 1.f / NPAD;
    #pragma unroll
    for (int j = 0; j < NPAD / 256; ++j) {
        int n = j * 256 + t;
        if (n < LENGTH) orow[n] = s[n] * scale + xr[n];
    }
}

extern "C" void kernel_launch(void* const* d_in, const int* in_sizes, int n_in,
                              void* d_out, int out_size, void* d_ws, size_t ws_size,
                              hipStream_t stream) {
    (void)in_sizes; (void)n_in; (void)out_size; (void)ws_size;
    const float* x = (const float*)d_in[0];
    const float* W = (const float*)d_in[1];
    const float* T = (const float*)d_in[2];
    const float* v = (const float*)d_in[3];
    float* out = (float*)d_out;
    float* f1 = (float*)d_ws;
    float* f6 = f1 + (size_t)NB * CH * NPAD;

    k_fwht_fwd<<<NB * CH, 256, 0, stream>>>(x, f1);
    k_mix<<<NB * (NPAD / NTILE), 256, 0, stream>>>(f1, W, T, v, f6);
    k_fwht_inv<<<NB * CH, 256, 0, stream>>>(f6, x, out);
}

// Round 7
// 41.497 us; speedup vs baseline: 6.1318x; 1.1265x over previous
//
#include <hip/hip_runtime.h>

#define LENGTH 4000
#define NPAD   4096
#define NB     8
#define CH     64
#define NP     4
#define NTILE  64               // n-columns per mix block

// 16-point unnormalized Sylvester FWHT, fully in registers (static indices).
__device__ __forceinline__ void fwht16(float v[16]) {
    #pragma unroll
    for (int h = 1; h < 16; h <<= 1)
        #pragma unroll
        for (int j = 0; j < 16; j += 2 * h)
            #pragma unroll
            for (int k = j; k < j + h; ++k) {
                float u = v[k], w = v[k + h];
                v[k] = u + w; v[k + h] = u - w;
            }
}

// ---------------- K1: forward FWHT (register radix-16^3) ----------------------
// n = A*256 + B*16 + C. Thread t = A*16+B loads 16 contiguous (C), H16 over C;
// LDS transpose -> H16 over B; LDS transpose -> H16 over A. 3 barriers total.
__global__ __launch_bounds__(256) void k_fwht_fwd(const float* __restrict__ x,
                                                  float* __restrict__ f1) {
    __shared__ float lds[256 * 17];        // padded stride 17: <=2-way bank alias
    const int row = blockIdx.x;            // b*64 + i
    const int t = threadIdx.x;
    const int A = t >> 4, B = t & 15;

    float v[16];
    if (t < 250) {                         // 250*16 == 4000: clean tail
        const float* xr = x + (size_t)row * LENGTH + t * 16;
        #pragma unroll
        for (int q = 0; q < 4; ++q) {
            float4 lv = *(const float4*)(xr + q * 4);
            v[q * 4 + 0] = lv.x; v[q * 4 + 1] = lv.y;
            v[q * 4 + 2] = lv.z; v[q * 4 + 3] = lv.w;
        }
    } else {
        #pragma unroll
        for (int c = 0; c < 16; ++c) v[c] = 0.f;
    }
    fwht16(v);                             // over C

    #pragma unroll
    for (int c = 0; c < 16; ++c)           // owner (A,C) gets slot B
        lds[(A * 16 + c) * 17 + B] = v[c];
    __syncthreads();
    {
        const int base = (A * 16 + B) * 17;// this thread now owns (A, C=t&15)
        #pragma unroll
        for (int b = 0; b < 16; ++b) v[b] = lds[base + b];
    }
    __syncthreads();                       // all L-reads done before overwrite
    fwht16(v);                             // over B

    const int C = t & 15;
    #pragma unroll
    for (int b = 0; b < 16; ++b)           // owner (B,C) gets slot A
        lds[(b * 16 + C) * 17 + A] = v[b];
    __syncthreads();
    {
        const int base2 = t * 17;          // (t>>4)*16 + (t&15) == t
        #pragma unroll
        for (int a = 0; a < 16; ++a) v[a] = lds[base2 + a];
    }
    fwht16(v);                             // over A

    float* fr = f1 + (size_t)row * NPAD;   // n = a*256 + t: contiguous per instr
    #pragma unroll
    for (int a = 0; a < 16; ++a)
        fr[a * 256 + t] = v[a];
}

// ---------------- K2: register-tiled channel mix (o-split for occupancy) ------
#define ST_APPLY(OUTC, AC, VPC, TPC)                                   \
    {                                                                  \
        float c_ = (VPC) * (AC);                                       \
        float aa_ = fabsf(c_) - fabsf(TPC);                            \
        (OUTC) += (aa_ > 0.f) ? copysignf(aa_, c_) : 0.f;              \
    }

__global__ __launch_bounds__(256) void k_mix(const float* __restrict__ f1,
                                             const float* __restrict__ W,
                                             const float* __restrict__ T,
                                             const float* __restrict__ v,
                                             float* __restrict__ f6) {
    __shared__ float sW[CH][32];           // [i][o-local], 8 KB
    __shared__ float sC[CH][NTILE];        // [i][n], 16 KB
    const int bid = blockIdx.x;            // b*128 + chunk*2 + oq
    const int oq = bid & 1;
    const int chunk = (bid >> 1) & 63;
    const int b = bid >> 7;
    const int nbase = chunk * NTILE;
    const int t = threadIdx.x;
    const int tn = t & 15, to = t >> 4;    // thread tile: 2 o x 4 n
    const int n0 = tn * 4;
    const int olocal = to * 2;
    const int og = oq * 32 + olocal;
    const int wo = t & 31, wib = t >> 5;   // W staging roles

    #pragma unroll
    for (int r = 0; r < 4; ++r) {          // stage f1 tile
        int q = r * 256 + t;
        int i = q >> 4, n4 = q & 15;
        *(float4*)(&sC[i][n4 * 4]) =
            *(const float4*)(f1 + (size_t)(b * CH + i) * NPAD + nbase + n4 * 4);
    }

    float4 out0, out1;
    out0.x = out0.y = out0.z = out0.w = 0.f; out1 = out0;

    #pragma unroll 1
    for (int p = 0; p < NP; ++p) {
        __syncthreads();                   // prior readers done (covers sC at p=0)
        const float* wp = W + (size_t)(p * CH + oq * 32 + wo) * CH + wib * 8;
        float4 wa = *(const float4*)(wp);
        float4 wb = *(const float4*)(wp + 4);
        sW[wib * 8 + 0][wo] = wa.x; sW[wib * 8 + 1][wo] = wa.y;
        sW[wib * 8 + 2][wo] = wa.z; sW[wib * 8 + 3][wo] = wa.w;
        sW[wib * 8 + 4][wo] = wb.x; sW[wib * 8 + 5][wo] = wb.y;
        sW[wib * 8 + 6][wo] = wb.z; sW[wib * 8 + 7][wo] = wb.w;
        __syncthreads();

        float4 a0, a1;
        a0.x = a0.y = a0.z = a0.w = 0.f; a1 = a0;
        #pragma unroll 8
        for (int i = 0; i < CH; ++i) {
            float2 w2 = *(const float2*)(&sW[i][olocal]); // 4-addr broadcast
            float4 c4 = *(const float4*)(&sC[i][n0]);     // dense, 2-way free
            a0.x = fmaf(w2.x, c4.x, a0.x); a0.y = fmaf(w2.x, c4.y, a0.y);
            a0.z = fmaf(w2.x, c4.z, a0.z); a0.w = fmaf(w2.x, c4.w, a0.w);
            a1.x = fmaf(w2.y, c4.x, a1.x); a1.y = fmaf(w2.y, c4.y, a1.y);
            a1.z = fmaf(w2.y, c4.z, a1.z); a1.w = fmaf(w2.y, c4.w, a1.w);
        }
        float4 vp = *(const float4*)(v + (size_t)p * NPAD + nbase + n0);
        float4 tp = *(const float4*)(T + (size_t)p * NPAD + nbase + n0);
        ST_APPLY(out0.x, a0.x, vp.x, tp.x); ST_APPLY(out0.y, a0.y, vp.y, tp.y);
        ST_APPLY(out0.z, a0.z, vp.z, tp.z); ST_APPLY(out0.w, a0.w, vp.w, tp.w);
        ST_APPLY(out1.x, a1.x, vp.x, tp.x); ST_APPLY(out1.y, a1.y, vp.y, tp.y);
        ST_APPLY(out1.z, a1.z, vp.z, tp.z); ST_APPLY(out1.w, a1.w, vp.w, tp.w);
    }

    float* dst = f6 + (size_t)(b * CH + og) * NPAD + nbase + n0;
    *(float4*)(dst) = out0;
    *(float4*)(dst + NPAD) = out1;
}

// ---------------- K3: inverse FWHT (register radix), scale, trunc, +x --------
__global__ __launch_bounds__(256) void k_fwht_inv(const float* __restrict__ f6,
                                                  const float* __restrict__ x,
                                                  float* __restrict__ out) {
    __shared__ float lds[256 * 17];
    const int row = blockIdx.x;            // b*64 + o
    const int t = threadIdx.x;
    const int A = t >> 4, B = t & 15;

    float v[16];
    {
        const float* fr = f6 + (size_t)row * NPAD + t * 16;
        #pragma unroll
        for (int q = 0; q < 4; ++q) {
            float4 lv = *(const float4*)(fr + q * 4);
            v[q * 4 + 0] = lv.x; v[q * 4 + 1] = lv.y;
            v[q * 4 + 2] = lv.z; v[q * 4 + 3] = lv.w;
        }
    }
    fwht16(v);

    #pragma unroll
    for (int c = 0; c < 16; ++c)
        lds[(A * 16 + c) * 17 + B] = v[c];
    __syncthreads();
    {
        const int base = (A * 16 + B) * 17;
        #pragma unroll
        for (int b = 0; b < 16; ++b) v[b] = lds[base + b];
    }
    __syncthreads();
    fwht16(v);

    const int C = t & 15;
    #pragma unroll
    for (int b = 0; b < 16; ++b)
        lds[(b * 16 + C) * 17 + A] = v[b];
    __syncthreads();
    {
        const int base2 = t * 17;
        #pragma unroll
        for (int a = 0; a < 16; ++a) v[a] = lds[base2 + a];
    }
    fwht16(v);

    const float scale = 1.f / NPAD;
    const float* xr = x + (size_t)row * LENGTH;
    float* orow = out + (size_t)row * LENGTH;
    #pragma unroll
    for (int a = 0; a < 16; ++a) {
        int n = a * 256 + t;
        if (n < LENGTH) orow[n] = v[a] * scale + xr[n];
    }
}

extern "C" void kernel_launch(void* const* d_in, const int* in_sizes, int n_in,
                              void* d_out, int out_size, void* d_ws, size_t ws_size,
                              hipStream_t stream) {
    (void)in_sizes; (void)n_in; (void)out_size; (void)ws_size;
    const float* x = (const float*)d_in[0];
    const float* W = (const float*)d_in[1];
    const float* T = (const float*)d_in[2];
    const float* v = (const float*)d_in[3];
    float* out = (float*)d_out;
    float* f1 = (float*)d_ws;
    float* f6 = f1 + (size_t)NB * CH * NPAD;

    k_fwht_fwd<<<NB * CH, 256, 0, stream>>>(x, f1);
    k_mix<<<NB * 64 * 2, 256, 0, stream>>>(f1, W, T, v, f6);
    k_fwht_inv<<<NB * CH, 256, 0, stream>>>(f6, x, out);
}